// Round 5
// baseline (277.297 us; speedup 1.0000x reference)
//
#include <hip/hip_runtime.h>

// Problem constants: N=8, LD=LM=1024, D=1024, H=16, HS=64
#define NB 8
#define LSEQ 1024
#define DMODEL 1024
#define NH 16
#define HS 64
#define KX 2048   // gemm contraction = 2*D

#define LOG2E 1.44269504f

typedef __bf16 bf16_t;
typedef __attribute__((ext_vector_type(4))) __bf16 bf16x4;
typedef __attribute__((ext_vector_type(8))) __bf16 bf16x8;
typedef __attribute__((ext_vector_type(4))) float floatx4;

typedef __attribute__((address_space(3))) unsigned int lds_u32;
typedef const __attribute__((address_space(1))) unsigned int glob_u32;

__device__ __forceinline__ floatx4 mfma16(bf16x8 a, bf16x8 b, floatx4 c) {
    return __builtin_amdgcn_mfma_f32_16x16x32_bf16(a, b, c, 0, 0, 0);
}
// async global->LDS, 16B/lane; dst wave-uniform base (lane*16 implicit)
__device__ __forceinline__ void gl_lds16(const bf16_t* g, bf16_t* l) {
    __builtin_amdgcn_global_load_lds((glob_u32*)g, (lds_u32*)l, 16, 0, 0);
}

// ---------------------------------------------------------------------------
// Kernel 0 (fused prep):
//  blocks [0,2048):    mem tile (n,h,kb 64x64): -> Mb (bf16) AND VTg (transposed)
//  blocks [2048,6144): input -> Xb[:,0:1024] (row stride 2048)
//  blocks [6144,7168): Wc -> Wb
//  blocks [7168,7176): mask -> biasG = (-1e30*(1-m) - 8) * log2e   (f32)
// ---------------------------------------------------------------------------
__global__ __launch_bounds__(256) void prep_kernel(
        const float* __restrict__ inp, const float* __restrict__ mem,
        const float* __restrict__ Wc, const float* __restrict__ mask,
        bf16_t* __restrict__ Xb, bf16_t* __restrict__ Mb,
        bf16_t* __restrict__ Wb, bf16_t* __restrict__ VTg,
        float* __restrict__ biasG) {
    __shared__ bf16_t Tl[64][72];
    const int tid = threadIdx.x;
    const int b = blockIdx.x;
    if (b < 2048) {
        const int kb = b & 15;
        const int h  = (b >> 4) & 15;
        const int n  = b >> 8;
        {   // phase 1: convert rows, write Mb + LDS tile
            const int key = tid >> 2, seg = tid & 3;
            const float* src = mem + ((size_t)(n * LSEQ + kb * 64 + key)) * DMODEL + h * HS + seg * 16;
            floatx4 f[4];
#pragma unroll
            for (int j = 0; j < 4; ++j) f[j] = *(const floatx4*)(src + j * 4);
            bf16x8 w0, w1;
#pragma unroll
            for (int j = 0; j < 8; ++j) { w0[j] = (bf16_t)f[j >> 2][j & 3]; w1[j] = (bf16_t)f[2 + (j >> 2)][j & 3]; }
            bf16_t* d = &Tl[key][seg * 16];
            *(bf16x8*)d = w0;
            *(bf16x8*)(d + 8) = w1;
            bf16_t* md = Mb + ((size_t)(n * LSEQ + kb * 64 + key)) * DMODEL + h * HS + seg * 16;
            *(bf16x8*)md = w0;
            *(bf16x8*)(md + 8) = w1;
        }
        __syncthreads();
        {   // phase 2: transposed write to VTg
            const int dim = tid >> 2, ks = tid & 3;
            bf16x8 w0, w1;
#pragma unroll
            for (int j = 0; j < 8; ++j) { w0[j] = Tl[ks * 16 + j][dim]; w1[j] = Tl[ks * 16 + 8 + j][dim]; }
            bf16_t* dst = VTg + ((size_t)((n * NH + h) * HS + dim)) * LSEQ + kb * 64 + ks * 16;
            *(bf16x8*)dst = w0;
            *(bf16x8*)(dst + 8) = w1;
        }
    } else if (b < 6144) {
        const size_t i8 = ((size_t)(b - 2048) * 256 + tid) * 8;
        floatx4 f0 = *(const floatx4*)(inp + i8);
        floatx4 f1 = *(const floatx4*)(inp + i8 + 4);
        bf16x8 w;
#pragma unroll
        for (int j = 0; j < 4; ++j) { w[j] = (bf16_t)f0[j]; w[4 + j] = (bf16_t)f1[j]; }
        *(bf16x8*)(Xb + (i8 >> 10) * KX + (i8 & 1023)) = w;
    } else if (b < 7168) {
        const size_t i8 = ((size_t)(b - 6144) * 256 + tid) * 8;
        floatx4 f0 = *(const floatx4*)(Wc + i8);
        floatx4 f1 = *(const floatx4*)(Wc + i8 + 4);
        bf16x8 w;
#pragma unroll
        for (int j = 0; j < 4; ++j) { w[j] = (bf16_t)f0[j]; w[4 + j] = (bf16_t)f1[j]; }
        *(bf16x8*)(Wb + i8) = w;
    } else {
        const size_t i4 = ((size_t)(b - 7168) * 256 + tid) * 4;
        floatx4 mv = *(const floatx4*)(mask + i4);
        floatx4 o;
#pragma unroll
        for (int j = 0; j < 4; ++j) o[j] = (-1e30f * (1.0f - mv[j]) - 8.0f) * LOG2E;
        *(floatx4*)(biasG + i4) = o;
    }
}

// ---------------------------------------------------------------------------
// Kernel 1: flash attention, S^T + static-shift softmax in exp2 domain.
// LDS = 16K (Kl) + 16K (Vl) + 8K (Pc) = 40 KB -> 4 blocks/CU.
// Bias (incl. -8 shift, *log2e) is the MFMA C-initializer, loaded from biasG.
// PV in 32-key chunks through 2KB/wave LDS with XOR(q&6) granule swizzle.
// ---------------------------------------------------------------------------
__global__ __launch_bounds__(256, 4) void attn_kernel(
        bf16_t* __restrict__ Xb, const bf16_t* __restrict__ Mb,
        const bf16_t* __restrict__ VTg, const float* __restrict__ biasG) {
    __shared__ __align__(16) bf16_t Kl[128 * 64];   // [key][dim sw]   16 KB
    __shared__ __align__(16) bf16_t Vl[64 * 128];   // [dim][key sw]   16 KB
    __shared__ __align__(16) bf16_t Pl[4 * 1024];   // per-wave P^T     8 KB

    const int tid  = threadIdx.x;
    const int lane = tid & 63;
    const int wv   = tid >> 6;
    const int ln15 = lane & 15;
    const int quad = lane >> 4;

    const int bid = blockIdx.x;      // 0..1023
    const int qt  = bid & 7;
    const int h   = (bid >> 3) & 15;
    const int n   = bid >> 7;
    const int q0  = qt * 128 + wv * 32;

    // Q B-frags pre-scaled by (1/sqrt(64))*log2e  -> scores in log2 domain
    bf16x8 qf[2][2];
#pragma unroll
    for (int nt = 0; nt < 2; ++nt) {
        const bf16_t* qp = Xb + ((size_t)(n * LSEQ + q0 + nt * 16 + ln15)) * KX + h * HS;
#pragma unroll
        for (int kk = 0; kk < 2; ++kk) {
            bf16x8 r = *(const bf16x8*)(qp + kk * 32 + quad * 8);
            bf16x8 a;
#pragma unroll
            for (int j = 0; j < 8; ++j) a[j] = (bf16_t)((float)r[j] * (0.125f * LOG2E));
            qf[nt][kk] = a;
        }
    }

    floatx4 ot[4][2];                 // O^T [dim-tile][ntile]
#pragma unroll
    for (int md = 0; md < 4; ++md)
#pragma unroll
        for (int nt = 0; nt < 2; ++nt) ot[md][nt] = (floatx4){0.f, 0.f, 0.f, 0.f};
    float lsum[2] = {0.f, 0.f};

    bf16_t* myP = &Pl[wv * 1024];     // 32 q x 32 keys, granule-swizzled
    const int qm = ln15 & 6;          // XOR mask (bit0 clear keeps b128 reads contiguous)

    for (int kt = 0; kt < LSEQ / 128; ++kt) {
        const int kb = kt * 128;
        __syncthreads();
        // ---- stage Kl: wave stages keys wv*32..+32 ----
#pragma unroll
        for (int i = 0; i < 4; ++i) {
            const int kbase = wv * 32 + i * 8;
            const int key = kbase + (lane >> 3), s = lane & 7, g = s ^ (key & 7);
            gl_lds16(Mb + ((size_t)(n * LSEQ + kb + key)) * DMODEL + h * HS + g * 8,
                     &Kl[kbase * 64]);
        }
        // ---- stage Vl: wave stages dims wv*16..+16 ----
#pragma unroll
        for (int i = 0; i < 4; ++i) {
            const int dbase = wv * 16 + i * 4;
            const int dim = dbase + (lane >> 4), s = lane & 15, g = s ^ (dim & 7);
            gl_lds16(VTg + ((size_t)((n * NH + h) * HS + dim)) * LSEQ + kb + g * 8,
                     &Vl[dbase * 128]);
        }
        __syncthreads();

#pragma unroll
        for (int half = 0; half < 2; ++half) {
            // ---- S^T (log2 domain) with C initialized to biasG ----
            floatx4 s4[4][2];
#pragma unroll
            for (int m = 0; m < 4; ++m) {
                const int key = half * 64 + m * 16 + ln15;
                floatx4 b4 = *(const floatx4*)(biasG + n * LSEQ + kb + half * 64 + m * 16 + quad * 4);
#pragma unroll
                for (int nt = 0; nt < 2; ++nt) s4[m][nt] = b4;
#pragma unroll
                for (int kk = 0; kk < 2; ++kk) {
                    const int slot = (kk * 4 + quad) ^ (ln15 & 7);
                    bf16x8 a = *(const bf16x8*)(&Kl[key * 64 + slot * 8]);
#pragma unroll
                    for (int nt = 0; nt < 2; ++nt) s4[m][nt] = mfma16(a, qf[nt][kk], s4[m][nt]);
                }
            }
            // ---- exp2 + per-lane l accumulation ----
#pragma unroll
            for (int m = 0; m < 4; ++m)
#pragma unroll
                for (int nt = 0; nt < 2; ++nt)
#pragma unroll
                    for (int reg = 0; reg < 4; ++reg) {
                        const float e = __builtin_amdgcn_exp2f(s4[m][nt][reg]);
                        s4[m][nt][reg] = e;
                        lsum[nt] += e;
                    }

            // ---- PV in 2 chunks of 32 keys through per-wave LDS ----
#pragma unroll
            for (int c = 0; c < 2; ++c) {
                // pack: m tiles {2c, 2c+1}; granule g = (m&1)*4+quad, XOR qm
#pragma unroll
                for (int mm = 0; mm < 2; ++mm) {
                    const int m = c * 2 + mm;
                    const int gsl = ((mm * 4 + quad) ^ qm) * 4;
#pragma unroll
                    for (int nt = 0; nt < 2; ++nt) {
                        const int q = nt * 16 + ln15;
                        bf16x4 p;
#pragma unroll
                        for (int reg = 0; reg < 4; ++reg) p[reg] = (bf16_t)s4[m][nt][reg];
                        *(bf16x4*)(&myP[q * 32 + gsl]) = p;
                    }
                }
                // read B-frags + MFMA
                const int cglob = half * 2 + c;
                bf16x8 pb[2];
#pragma unroll
                for (int nt = 0; nt < 2; ++nt) {
                    const int q = nt * 16 + ln15;
                    const int s16 = quad ^ (qm >> 1);
                    pb[nt] = *(const bf16x8*)(&myP[q * 32 + s16 * 8]);
                }
#pragma unroll
                for (int md = 0; md < 4; ++md) {
                    const int d = md * 16 + ln15;
                    const int vslot = (cglob * 4 + quad) ^ (d & 7);
                    bf16x8 va = *(const bf16x8*)(&Vl[d * 128 + vslot * 8]);
#pragma unroll
                    for (int nt = 0; nt < 2; ++nt) ot[md][nt] = mfma16(va, pb[nt], ot[md][nt]);
                }
            }
        }
    }

    // ---- reduce l across quads (once), write ctx^T -> Xb[:,1024:2048] ----
#pragma unroll
    for (int nt = 0; nt < 2; ++nt) {
        float t = lsum[nt];
        t += __shfl_xor(t, 16);
        t += __shfl_xor(t, 32);
        const float inv = 1.0f / t;
        const int q = q0 + nt * 16 + ln15;
        bf16_t* op = Xb + ((size_t)(n * LSEQ + q)) * KX + DMODEL + h * HS;
#pragma unroll
        for (int md = 0; md < 4; ++md) {
            bf16x4 w;
#pragma unroll
            for (int reg = 0; reg < 4; ++reg) w[reg] = (bf16_t)(ot[md][nt][reg] * inv);
            *(bf16x4*)(op + md * 16 + quad * 4) = w;
        }
    }
}

// ---------------------------------------------------------------------------
// Kernel 2: out = act( Xb @ Wb^T + bc ),  act(z)=sigmoid(z)*tanh(z).
// M=8192, N=1024, K=2048.  BM=128, BN=64, BK=64, 256 thr.
// Double-buffered LDS (48 KB, 3 blocks/CU): gl_lds16 for tile t+1 issued
// before compute of tile t; ONE barrier per iter (vmcnt drain overlaps MFMA).
// ---------------------------------------------------------------------------
__global__ __launch_bounds__(256, 3) void gemm_kernel(
        const bf16_t* __restrict__ Xb, const bf16_t* __restrict__ Wb,
        const float* __restrict__ bc, float* __restrict__ out) {
    __shared__ __align__(16) bf16_t Al[2][128 * 64];   // 32 KB
    __shared__ __align__(16) bf16_t Bl[2][64 * 64];    // 16 KB

    const int tid  = threadIdx.x;
    const int lane = tid & 63;
    const int wv   = tid >> 6;          // 0..3
    const int ln15 = lane & 15;
    const int quad = lane >> 4;

    const int bn = blockIdx.x & 15;
    const int bm = blockIdx.x >> 4;
    const int mbase = bm * 128, nbase = bn * 64;

    const int arow8 = lane >> 3;                    // staging helpers
    const int ag    = (lane & 7);

    floatx4 acc[2][4];
#pragma unroll
    for (int i = 0; i < 2; ++i)
#pragma unroll
        for (int j = 0; j < 4; ++j) acc[i][j] = (floatx4){0.f, 0.f, 0.f, 0.f};

    // prologue: stage tile 0 into buf 0
#pragma unroll
    for (int i = 0; i < 4; ++i) {
        const int r0  = i * 32 + wv * 8;
        const int row = r0 + arow8;
        const int g   = ag ^ (row & 7);
        gl_lds16(Xb + (size_t)(mbase + row) * KX + g * 8, &Al[0][r0 * 64]);
    }
#pragma unroll
    for (int j = 0; j < 2; ++j) {
        const int r0  = j * 32 + wv * 8;
        const int row = r0 + arow8;
        const int g   = ag ^ (row & 7);
        gl_lds16(Wb + (size_t)(nbase + row) * KX + g * 8, &Bl[0][r0 * 64]);
    }
    __syncthreads();

    for (int it = 0; it < KX / 64; ++it) {
        const int cur = it & 1;
        if (it < KX / 64 - 1) {
            const int k1 = (it + 1) * 64;
#pragma unroll
            for (int i = 0; i < 4; ++i) {
                const int r0  = i * 32 + wv * 8;
                const int row = r0 + arow8;
                const int g   = ag ^ (row & 7);
                gl_lds16(Xb + (size_t)(mbase + row) * KX + k1 + g * 8, &Al[cur ^ 1][r0 * 64]);
            }
#pragma unroll
            for (int j = 0; j < 2; ++j) {
                const int r0  = j * 32 + wv * 8;
                const int row = r0 + arow8;
                const int g   = ag ^ (row & 7);
                gl_lds16(Wb + (size_t)(nbase + row) * KX + k1 + g * 8, &Bl[cur ^ 1][r0 * 64]);
            }
        }

#pragma unroll
        for (int kk = 0; kk < 2; ++kk) {
            bf16x8 af[2], bfr[4];
#pragma unroll
            for (int mi = 0; mi < 2; ++mi) {
                const int row = wv * 32 + mi * 16 + ln15;
                const int slot = (kk * 4 + quad) ^ (row & 7);
                af[mi] = *(const bf16x8*)(&Al[cur][row * 64 + slot * 8]);
            }
#pragma unroll
            for (int ni = 0; ni < 4; ++ni) {
                const int row = ni * 16 + ln15;
                const int slot = (kk * 4 + quad) ^ (row & 7);
                bfr[ni] = *(const bf16x8*)(&Bl[cur][row * 64 + slot * 8]);
            }
#pragma unroll
            for (int mi = 0; mi < 2; ++mi)
#pragma unroll
                for (int ni = 0; ni < 4; ++ni)
                    acc[mi][ni] = mfma16(af[mi], bfr[ni], acc[mi][ni]);
        }
        __syncthreads();   // drains next-tile vmcnt (overlapped with MFMA above)
    }

    // epilogue: bias + sigmoid(z)*tanh(z)
#pragma unroll
    for (int ni = 0; ni < 4; ++ni) {
        const int col = nbase + ni * 16 + ln15;
        const float b = bc[col];
#pragma unroll
        for (int mi = 0; mi < 2; ++mi) {
#pragma unroll
            for (int reg = 0; reg < 4; ++reg) {
                const int row = mbase + wv * 32 + mi * 16 + quad * 4 + reg;
                const float z  = acc[mi][ni][reg] + b;
                const float sg = 1.0f / (1.0f + __expf(-z));
                const float th = 2.0f / (1.0f + __expf(-2.0f * z)) - 1.0f;
                out[(size_t)row * 1024 + col] = sg * th;
            }
        }
    }
}

extern "C" void kernel_launch(void* const* d_in, const int* in_sizes, int n_in,
                              void* d_out, int out_size, void* d_ws, size_t ws_size,
                              hipStream_t stream) {
    const float* inp  = (const float*)d_in[0];
    const float* mem  = (const float*)d_in[1];
    const float* mask = (const float*)d_in[2];
    const float* Wc   = (const float*)d_in[3];
    const float* bc   = (const float*)d_in[4];
    float* out = (float*)d_out;

    // ws: Xb [8192][2048] (32M) | Mb [8192][1024] (16M) | Wb [1024][2048] (4M)
    //     | VTg [8][16][64][1024] (16M) | biasG [8][1024] f32 (32K)
    bf16_t* Xb  = (bf16_t*)d_ws;
    bf16_t* Mb  = Xb + (size_t)8192 * 2048;
    bf16_t* Wb  = Mb + (size_t)8192 * 1024;
    bf16_t* VTg = Wb + (size_t)1024 * 2048;
    float* biasG = (float*)(VTg + (size_t)8192 * 1024);

    prep_kernel<<<7176, 256, 0, stream>>>(inp, mem, Wc, mask, Xb, Mb, Wb, VTg, biasG);
    attn_kernel<<<NB * NH * (LSEQ / 128), 256, 0, stream>>>(Xb, Mb, VTg, biasG);
    gemm_kernel<<<(8192 / 128) * (1024 / 64), 256, 0, stream>>>(Xb, Wb, bc, out);
}

// Round 6
// 235.055 us; speedup vs baseline: 1.1797x; 1.1797x over previous
//
#include <hip/hip_runtime.h>

// Problem constants: N=8, LD=LM=1024, D=1024, H=16, HS=64
#define NB 8
#define LSEQ 1024
#define DMODEL 1024
#define NH 16
#define HS 64
#define KX 2048   // gemm contraction = 2*D

#define LOG2E 1.44269504f

typedef __bf16 bf16_t;
typedef __attribute__((ext_vector_type(4))) __bf16 bf16x4;
typedef __attribute__((ext_vector_type(8))) __bf16 bf16x8;
typedef __attribute__((ext_vector_type(4))) float floatx4;

typedef __attribute__((address_space(3))) unsigned int lds_u32;
typedef const __attribute__((address_space(1))) unsigned int glob_u32;

__device__ __forceinline__ floatx4 mfma16(bf16x8 a, bf16x8 b, floatx4 c) {
    return __builtin_amdgcn_mfma_f32_16x16x32_bf16(a, b, c, 0, 0, 0);
}
// async global->LDS, 16B/lane; dst wave-uniform base (lane*16 implicit)
__device__ __forceinline__ void gl_lds16(const bf16_t* g, bf16_t* l) {
    __builtin_amdgcn_global_load_lds((glob_u32*)g, (lds_u32*)l, 16, 0, 0);
}

// ---------------------------------------------------------------------------
// Kernel 0 (fused prep):
//  blocks [0,2048):    mem tile (n,h,kb 64x64): -> Mb (bf16) AND VTg (transposed)
//  blocks [2048,6144): input -> Xb[:,0:1024] (row stride 2048)
//  blocks [6144,7168): Wc -> Wb
//  blocks [7168,7176): mask -> biasG = (-1e30*(1-m) - 8) * log2e   (f32)
// ---------------------------------------------------------------------------
__global__ __launch_bounds__(256) void prep_kernel(
        const float* __restrict__ inp, const float* __restrict__ mem,
        const float* __restrict__ Wc, const float* __restrict__ mask,
        bf16_t* __restrict__ Xb, bf16_t* __restrict__ Mb,
        bf16_t* __restrict__ Wb, bf16_t* __restrict__ VTg,
        float* __restrict__ biasG) {
    __shared__ bf16_t Tl[64][72];
    const int tid = threadIdx.x;
    const int b = blockIdx.x;
    if (b < 2048) {
        const int kb = b & 15;
        const int h  = (b >> 4) & 15;
        const int n  = b >> 8;
        {   // phase 1: convert rows, write Mb + LDS tile
            const int key = tid >> 2, seg = tid & 3;
            const float* src = mem + ((size_t)(n * LSEQ + kb * 64 + key)) * DMODEL + h * HS + seg * 16;
            floatx4 f[4];
#pragma unroll
            for (int j = 0; j < 4; ++j) f[j] = *(const floatx4*)(src + j * 4);
            bf16x8 w0, w1;
#pragma unroll
            for (int j = 0; j < 8; ++j) { w0[j] = (bf16_t)f[j >> 2][j & 3]; w1[j] = (bf16_t)f[2 + (j >> 2)][j & 3]; }
            bf16_t* d = &Tl[key][seg * 16];
            *(bf16x8*)d = w0;
            *(bf16x8*)(d + 8) = w1;
            bf16_t* md = Mb + ((size_t)(n * LSEQ + kb * 64 + key)) * DMODEL + h * HS + seg * 16;
            *(bf16x8*)md = w0;
            *(bf16x8*)(md + 8) = w1;
        }
        __syncthreads();
        {   // phase 2: transposed write to VTg
            const int dim = tid >> 2, ks = tid & 3;
            bf16x8 w0, w1;
#pragma unroll
            for (int j = 0; j < 8; ++j) { w0[j] = Tl[ks * 16 + j][dim]; w1[j] = Tl[ks * 16 + 8 + j][dim]; }
            bf16_t* dst = VTg + ((size_t)((n * NH + h) * HS + dim)) * LSEQ + kb * 64 + ks * 16;
            *(bf16x8*)dst = w0;
            *(bf16x8*)(dst + 8) = w1;
        }
    } else if (b < 6144) {
        const size_t i8 = ((size_t)(b - 2048) * 256 + tid) * 8;
        floatx4 f0 = *(const floatx4*)(inp + i8);
        floatx4 f1 = *(const floatx4*)(inp + i8 + 4);
        bf16x8 w;
#pragma unroll
        for (int j = 0; j < 4; ++j) { w[j] = (bf16_t)f0[j]; w[4 + j] = (bf16_t)f1[j]; }
        *(bf16x8*)(Xb + (i8 >> 10) * KX + (i8 & 1023)) = w;
    } else if (b < 7168) {
        const size_t i8 = ((size_t)(b - 6144) * 256 + tid) * 8;
        floatx4 f0 = *(const floatx4*)(Wc + i8);
        floatx4 f1 = *(const floatx4*)(Wc + i8 + 4);
        bf16x8 w;
#pragma unroll
        for (int j = 0; j < 4; ++j) { w[j] = (bf16_t)f0[j]; w[4 + j] = (bf16_t)f1[j]; }
        *(bf16x8*)(Wb + i8) = w;
    } else {
        const size_t i4 = ((size_t)(b - 7168) * 256 + tid) * 4;
        floatx4 mv = *(const floatx4*)(mask + i4);
        floatx4 o;
#pragma unroll
        for (int j = 0; j < 4; ++j) o[j] = (-1e30f * (1.0f - mv[j]) - 8.0f) * LOG2E;
        *(floatx4*)(biasG + i4) = o;
    }
}

// ---------------------------------------------------------------------------
// Kernel 1: flash attention, S^T + static-shift softmax in exp2 domain.
// LDS = 16K (Kl) + 16K (Vl) + 8K (Pl) = 40 KB -> 4 blocks/CU when VGPR<=128.
// NO min-waves launch_bounds clause: R5's (256,4) forced VGPR=64 -> scratch
// spill (WRITE_SIZE 16KB->101MB).  Compiler's natural ~116 VGPR fits 4/EU.
// ---------------------------------------------------------------------------
__global__ __launch_bounds__(256) void attn_kernel(
        bf16_t* __restrict__ Xb, const bf16_t* __restrict__ Mb,
        const bf16_t* __restrict__ VTg, const float* __restrict__ biasG) {
    __shared__ __align__(16) bf16_t Kl[128 * 64];   // [key][dim sw]   16 KB
    __shared__ __align__(16) bf16_t Vl[64 * 128];   // [dim][key sw]   16 KB
    __shared__ __align__(16) bf16_t Pl[4 * 1024];   // per-wave P^T     8 KB

    const int tid  = threadIdx.x;
    const int lane = tid & 63;
    const int wv   = tid >> 6;
    const int ln15 = lane & 15;
    const int quad = lane >> 4;

    const int bid = blockIdx.x;      // 0..1023
    const int qt  = bid & 7;
    const int h   = (bid >> 3) & 15;
    const int n   = bid >> 7;
    const int q0  = qt * 128 + wv * 32;

    // Q B-frags pre-scaled by (1/sqrt(64))*log2e  -> scores in log2 domain
    bf16x8 qf[2][2];
#pragma unroll
    for (int nt = 0; nt < 2; ++nt) {
        const bf16_t* qp = Xb + ((size_t)(n * LSEQ + q0 + nt * 16 + ln15)) * KX + h * HS;
#pragma unroll
        for (int kk = 0; kk < 2; ++kk) {
            bf16x8 r = *(const bf16x8*)(qp + kk * 32 + quad * 8);
            bf16x8 a;
#pragma unroll
            for (int j = 0; j < 8; ++j) a[j] = (bf16_t)((float)r[j] * (0.125f * LOG2E));
            qf[nt][kk] = a;
        }
    }

    floatx4 ot[4][2];                 // O^T [dim-tile][ntile]
#pragma unroll
    for (int md = 0; md < 4; ++md)
#pragma unroll
        for (int nt = 0; nt < 2; ++nt) ot[md][nt] = (floatx4){0.f, 0.f, 0.f, 0.f};
    float lsum[2] = {0.f, 0.f};

    bf16_t* myP = &Pl[wv * 1024];     // 32 q x 32 keys, granule-swizzled
    const int qm = ln15 & 6;          // XOR mask (bit0 clear keeps b128 reads contiguous)

    for (int kt = 0; kt < LSEQ / 128; ++kt) {
        const int kb = kt * 128;
        __syncthreads();
        // ---- stage Kl: wave stages keys wv*32..+32 ----
#pragma unroll
        for (int i = 0; i < 4; ++i) {
            const int kbase = wv * 32 + i * 8;
            const int key = kbase + (lane >> 3), s = lane & 7, g = s ^ (key & 7);
            gl_lds16(Mb + ((size_t)(n * LSEQ + kb + key)) * DMODEL + h * HS + g * 8,
                     &Kl[kbase * 64]);
        }
        // ---- stage Vl: wave stages dims wv*16..+16 ----
#pragma unroll
        for (int i = 0; i < 4; ++i) {
            const int dbase = wv * 16 + i * 4;
            const int dim = dbase + (lane >> 4), s = lane & 15, g = s ^ (dim & 7);
            gl_lds16(VTg + ((size_t)((n * NH + h) * HS + dim)) * LSEQ + kb + g * 8,
                     &Vl[dbase * 128]);
        }
        __syncthreads();

#pragma unroll
        for (int half = 0; half < 2; ++half) {
            // ---- S^T (log2 domain) with C initialized to biasG ----
            floatx4 s4[4][2];
#pragma unroll
            for (int m = 0; m < 4; ++m) {
                const int key = half * 64 + m * 16 + ln15;
                floatx4 b4 = *(const floatx4*)(biasG + n * LSEQ + kb + half * 64 + m * 16 + quad * 4);
#pragma unroll
                for (int nt = 0; nt < 2; ++nt) s4[m][nt] = b4;
#pragma unroll
                for (int kk = 0; kk < 2; ++kk) {
                    const int slot = (kk * 4 + quad) ^ (ln15 & 7);
                    bf16x8 a = *(const bf16x8*)(&Kl[key * 64 + slot * 8]);
#pragma unroll
                    for (int nt = 0; nt < 2; ++nt) s4[m][nt] = mfma16(a, qf[nt][kk], s4[m][nt]);
                }
            }
            // ---- exp2 + per-lane l accumulation ----
#pragma unroll
            for (int m = 0; m < 4; ++m)
#pragma unroll
                for (int nt = 0; nt < 2; ++nt)
#pragma unroll
                    for (int reg = 0; reg < 4; ++reg) {
                        const float e = __builtin_amdgcn_exp2f(s4[m][nt][reg]);
                        s4[m][nt][reg] = e;
                        lsum[nt] += e;
                    }

            // ---- PV in 2 chunks of 32 keys through per-wave LDS ----
#pragma unroll
            for (int c = 0; c < 2; ++c) {
                // pack: m tiles {2c, 2c+1}; granule g = (m&1)*4+quad, XOR qm
#pragma unroll
                for (int mm = 0; mm < 2; ++mm) {
                    const int m = c * 2 + mm;
                    const int gsl = ((mm * 4 + quad) ^ qm) * 4;
#pragma unroll
                    for (int nt = 0; nt < 2; ++nt) {
                        const int q = nt * 16 + ln15;
                        bf16x4 p;
#pragma unroll
                        for (int reg = 0; reg < 4; ++reg) p[reg] = (bf16_t)s4[m][nt][reg];
                        *(bf16x4*)(&myP[q * 32 + gsl]) = p;
                    }
                }
                // read B-frags + MFMA
                const int cglob = half * 2 + c;
                bf16x8 pb[2];
#pragma unroll
                for (int nt = 0; nt < 2; ++nt) {
                    const int q = nt * 16 + ln15;
                    const int s16 = quad ^ (qm >> 1);
                    pb[nt] = *(const bf16x8*)(&myP[q * 32 + s16 * 8]);
                }
#pragma unroll
                for (int md = 0; md < 4; ++md) {
                    const int d = md * 16 + ln15;
                    const int vslot = (cglob * 4 + quad) ^ (d & 7);
                    bf16x8 va = *(const bf16x8*)(&Vl[d * 128 + vslot * 8]);
#pragma unroll
                    for (int nt = 0; nt < 2; ++nt) ot[md][nt] = mfma16(va, pb[nt], ot[md][nt]);
                }
            }
        }
    }

    // ---- reduce l across quads (once), write ctx^T -> Xb[:,1024:2048] ----
#pragma unroll
    for (int nt = 0; nt < 2; ++nt) {
        float t = lsum[nt];
        t += __shfl_xor(t, 16);
        t += __shfl_xor(t, 32);
        const float inv = 1.0f / t;
        const int q = q0 + nt * 16 + ln15;
        bf16_t* op = Xb + ((size_t)(n * LSEQ + q)) * KX + DMODEL + h * HS;
#pragma unroll
        for (int md = 0; md < 4; ++md) {
            bf16x4 w;
#pragma unroll
            for (int reg = 0; reg < 4; ++reg) w[reg] = (bf16_t)(ot[md][nt][reg] * inv);
            *(bf16x4*)(op + md * 16 + quad * 4) = w;
        }
    }
}

// ---------------------------------------------------------------------------
// Kernel 2: out = act( Xb @ Wb^T + bc ),  act(z)=sigmoid(z)*tanh(z).
// M=8192, N=1024, K=2048.  BM=128, BN=64, BK=64, 256 thr (4 waves).
// Single-buffered 24 KB LDS; grid 1024 = 4 blocks/CU (launch_bounds(256,4)
// is safe here: kernel needs ~64 VGPRs, no spill risk).  R5's 48KB dbuf
// at 3 blocks/CU was no better (m99/m100 pattern) -- reverted.
// ---------------------------------------------------------------------------
__global__ __launch_bounds__(256, 4) void gemm_kernel(
        const bf16_t* __restrict__ Xb, const bf16_t* __restrict__ Wb,
        const float* __restrict__ bc, float* __restrict__ out) {
    __shared__ __align__(16) bf16_t Al[128 * 64];   // 16 KB
    __shared__ __align__(16) bf16_t Bl[64 * 64];    //  8 KB

    const int tid  = threadIdx.x;
    const int lane = tid & 63;
    const int wv   = tid >> 6;          // 0..3
    const int ln15 = lane & 15;
    const int quad = lane >> 4;

    const int bn = blockIdx.x & 15;
    const int bm = blockIdx.x >> 4;
    const int mbase = bm * 128, nbase = bn * 64;

    floatx4 acc[2][4];
#pragma unroll
    for (int i = 0; i < 2; ++i)
#pragma unroll
        for (int j = 0; j < 4; ++j) acc[i][j] = (floatx4){0.f, 0.f, 0.f, 0.f};

    for (int it = 0; it < KX / 64; ++it) {
        const int k0 = it * 64;
        __syncthreads();
        // A: 128 rows x 64 cols, 4 issues/wave (8 rows each)
#pragma unroll
        for (int i = 0; i < 4; ++i) {
            const int r0  = i * 32 + wv * 8;
            const int row = r0 + (lane >> 3);
            const int g   = (lane & 7) ^ (row & 7);
            gl_lds16(Xb + (size_t)(mbase + row) * KX + k0 + g * 8, &Al[r0 * 64]);
        }
        // B: 64 rows x 64 cols, 2 issues/wave
#pragma unroll
        for (int j = 0; j < 2; ++j) {
            const int r0  = j * 32 + wv * 8;
            const int row = r0 + (lane >> 3);
            const int g   = (lane & 7) ^ (row & 7);
            gl_lds16(Wb + (size_t)(nbase + row) * KX + k0 + g * 8, &Bl[r0 * 64]);
        }
        __syncthreads();

#pragma unroll
        for (int kk = 0; kk < 2; ++kk) {
            bf16x8 af[2], bfr[4];
#pragma unroll
            for (int mi = 0; mi < 2; ++mi) {
                const int row = wv * 32 + mi * 16 + ln15;
                const int slot = (kk * 4 + quad) ^ (row & 7);
                af[mi] = *(const bf16x8*)(&Al[row * 64 + slot * 8]);
            }
#pragma unroll
            for (int ni = 0; ni < 4; ++ni) {
                const int row = ni * 16 + ln15;
                const int slot = (kk * 4 + quad) ^ (row & 7);
                bfr[ni] = *(const bf16x8*)(&Bl[row * 64 + slot * 8]);
            }
#pragma unroll
            for (int mi = 0; mi < 2; ++mi)
#pragma unroll
                for (int ni = 0; ni < 4; ++ni)
                    acc[mi][ni] = mfma16(af[mi], bfr[ni], acc[mi][ni]);
        }
    }

    // epilogue: bias + sigmoid(z)*tanh(z)
#pragma unroll
    for (int ni = 0; ni < 4; ++ni) {
        const int col = nbase + ni * 16 + ln15;
        const float b = bc[col];
#pragma unroll
        for (int mi = 0; mi < 2; ++mi) {
#pragma unroll
            for (int reg = 0; reg < 4; ++reg) {
                const int row = mbase + wv * 32 + mi * 16 + quad * 4 + reg;
                const float z  = acc[mi][ni][reg] + b;
                const float sg = 1.0f / (1.0f + __expf(-z));
                const float th = 2.0f / (1.0f + __expf(-2.0f * z)) - 1.0f;
                out[(size_t)row * 1024 + col] = sg * th;
            }
        }
    }
}

extern "C" void kernel_launch(void* const* d_in, const int* in_sizes, int n_in,
                              void* d_out, int out_size, void* d_ws, size_t ws_size,
                              hipStream_t stream) {
    const float* inp  = (const float*)d_in[0];
    const float* mem  = (const float*)d_in[1];
    const float* mask = (const float*)d_in[2];
    const float* Wc   = (const float*)d_in[3];
    const float* bc   = (const float*)d_in[4];
    float* out = (float*)d_out;

    // ws: Xb [8192][2048] (32M) | Mb [8192][1024] (16M) | Wb [1024][2048] (4M)
    //     | VTg [8][16][64][1024] (16M) | biasG [8][1024] f32 (32K)
    bf16_t* Xb  = (bf16_t*)d_ws;
    bf16_t* Mb  = Xb + (size_t)8192 * 2048;
    bf16_t* Wb  = Mb + (size_t)8192 * 1024;
    bf16_t* VTg = Wb + (size_t)1024 * 2048;
    float* biasG = (float*)(VTg + (size_t)8192 * 1024);

    prep_kernel<<<7176, 256, 0, stream>>>(inp, mem, Wc, mask, Xb, Mb, Wb, VTg, biasG);
    attn_kernel<<<NB * NH * (LSEQ / 128), 256, 0, stream>>>(Xb, Mb, VTg, biasG);
    gemm_kernel<<<(8192 / 128) * (1024 / 64), 256, 0, stream>>>(Xb, Wb, bc, out);
}

// Round 7
// 216.274 us; speedup vs baseline: 1.2822x; 1.0868x over previous
//
#include <hip/hip_runtime.h>

// Problem constants: N=8, LD=LM=1024, D=1024, H=16, HS=64
#define NB 8
#define LSEQ 1024
#define DMODEL 1024
#define NH 16
#define HS 64
#define KX 2048   // gemm contraction = 2*D

#define LOG2E 1.44269504f

typedef __bf16 bf16_t;
typedef __attribute__((ext_vector_type(4))) __bf16 bf16x4;
typedef __attribute__((ext_vector_type(8))) __bf16 bf16x8;
typedef __attribute__((ext_vector_type(4))) float floatx4;

typedef __attribute__((address_space(3))) unsigned int lds_u32;
typedef const __attribute__((address_space(1))) unsigned int glob_u32;

__device__ __forceinline__ floatx4 mfma16(bf16x8 a, bf16x8 b, floatx4 c) {
    return __builtin_amdgcn_mfma_f32_16x16x32_bf16(a, b, c, 0, 0, 0);
}
// async global->LDS, 16B/lane; dst wave-uniform base (lane*16 implicit)
__device__ __forceinline__ void gl_lds16(const bf16_t* g, bf16_t* l) {
    __builtin_amdgcn_global_load_lds((glob_u32*)g, (lds_u32*)l, 16, 0, 0);
}

// ---------------------------------------------------------------------------
// Kernel 0 (fused prep):
//  blocks [0,2048):    mem tile (n,h,kb 64x64): -> Mb (bf16) AND VTg (transposed)
//  blocks [2048,6144): input -> Xb[:,0:1024] (row stride 2048)
//  blocks [6144,7168): Wc -> Wb
//  blocks [7168,7176): mask -> biasG = (-1e30*(1-m) - 8) * log2e   (f32)
// ---------------------------------------------------------------------------
__global__ __launch_bounds__(256) void prep_kernel(
        const float* __restrict__ inp, const float* __restrict__ mem,
        const float* __restrict__ Wc, const float* __restrict__ mask,
        bf16_t* __restrict__ Xb, bf16_t* __restrict__ Mb,
        bf16_t* __restrict__ Wb, bf16_t* __restrict__ VTg,
        float* __restrict__ biasG) {
    __shared__ bf16_t Tl[64][72];
    const int tid = threadIdx.x;
    const int b = blockIdx.x;
    if (b < 2048) {
        const int kb = b & 15;
        const int h  = (b >> 4) & 15;
        const int n  = b >> 8;
        {   // phase 1: convert rows, write Mb + LDS tile
            const int key = tid >> 2, seg = tid & 3;
            const float* src = mem + ((size_t)(n * LSEQ + kb * 64 + key)) * DMODEL + h * HS + seg * 16;
            floatx4 f[4];
#pragma unroll
            for (int j = 0; j < 4; ++j) f[j] = *(const floatx4*)(src + j * 4);
            bf16x8 w0, w1;
#pragma unroll
            for (int j = 0; j < 8; ++j) { w0[j] = (bf16_t)f[j >> 2][j & 3]; w1[j] = (bf16_t)f[2 + (j >> 2)][j & 3]; }
            bf16_t* d = &Tl[key][seg * 16];
            *(bf16x8*)d = w0;
            *(bf16x8*)(d + 8) = w1;
            bf16_t* md = Mb + ((size_t)(n * LSEQ + kb * 64 + key)) * DMODEL + h * HS + seg * 16;
            *(bf16x8*)md = w0;
            *(bf16x8*)(md + 8) = w1;
        }
        __syncthreads();
        {   // phase 2: transposed write to VTg
            const int dim = tid >> 2, ks = tid & 3;
            bf16x8 w0, w1;
#pragma unroll
            for (int j = 0; j < 8; ++j) { w0[j] = Tl[ks * 16 + j][dim]; w1[j] = Tl[ks * 16 + 8 + j][dim]; }
            bf16_t* dst = VTg + ((size_t)((n * NH + h) * HS + dim)) * LSEQ + kb * 64 + ks * 16;
            *(bf16x8*)dst = w0;
            *(bf16x8*)(dst + 8) = w1;
        }
    } else if (b < 6144) {
        const size_t i8 = ((size_t)(b - 2048) * 256 + tid) * 8;
        floatx4 f0 = *(const floatx4*)(inp + i8);
        floatx4 f1 = *(const floatx4*)(inp + i8 + 4);
        bf16x8 w;
#pragma unroll
        for (int j = 0; j < 4; ++j) { w[j] = (bf16_t)f0[j]; w[4 + j] = (bf16_t)f1[j]; }
        *(bf16x8*)(Xb + (i8 >> 10) * KX + (i8 & 1023)) = w;
    } else if (b < 7168) {
        const size_t i8 = ((size_t)(b - 6144) * 256 + tid) * 8;
        floatx4 f0 = *(const floatx4*)(Wc + i8);
        floatx4 f1 = *(const floatx4*)(Wc + i8 + 4);
        bf16x8 w;
#pragma unroll
        for (int j = 0; j < 4; ++j) { w[j] = (bf16_t)f0[j]; w[4 + j] = (bf16_t)f1[j]; }
        *(bf16x8*)(Wb + i8) = w;
    } else {
        const size_t i4 = ((size_t)(b - 7168) * 256 + tid) * 4;
        floatx4 mv = *(const floatx4*)(mask + i4);
        floatx4 o;
#pragma unroll
        for (int j = 0; j < 4; ++j) o[j] = (-1e30f * (1.0f - mv[j]) - 8.0f) * LOG2E;
        *(floatx4*)(biasG + i4) = o;
    }
}

// ---------------------------------------------------------------------------
// Kernel 1: flash attention, S^T + static-shift softmax in exp2 domain.
// LDS 40 KB, VGPR ~84 (no min-waves clause -- R5's (256,4) caused spill).
// XCD-LOCALITY SWIZZLE: bid = qt*128 + (n*16+h)  =>  XCD = bid&7 = h&7,
// so all 8 q-tile blocks of one (n,h) share an XCD; per-XCD K+V working
// set = 16 heads x 256 KB = 4 MB = one L2.  Kills the 3x HBM re-fetch
// (R6: FETCH 139 MB vs 48 MB ideal; 8 q-tiles hit 8 different L2s).
// ---------------------------------------------------------------------------
__global__ __launch_bounds__(256) void attn_kernel(
        bf16_t* __restrict__ Xb, const bf16_t* __restrict__ Mb,
        const bf16_t* __restrict__ VTg, const float* __restrict__ biasG) {
    __shared__ __align__(16) bf16_t Kl[128 * 64];   // [key][dim sw]   16 KB
    __shared__ __align__(16) bf16_t Vl[64 * 128];   // [dim][key sw]   16 KB
    __shared__ __align__(16) bf16_t Pl[4 * 1024];   // per-wave P^T     8 KB

    const int tid  = threadIdx.x;
    const int lane = tid & 63;
    const int wv   = tid >> 6;
    const int ln15 = lane & 15;
    const int quad = lane >> 4;

    const int bid = blockIdx.x;      // 0..1023
    const int nh  = bid & 127;       // (n*16+h): XCD = h&7
    const int qt  = bid >> 7;
    const int h   = nh & 15;
    const int n   = nh >> 4;
    const int q0  = qt * 128 + wv * 32;

    // Q B-frags pre-scaled by (1/sqrt(64))*log2e  -> scores in log2 domain
    bf16x8 qf[2][2];
#pragma unroll
    for (int nt = 0; nt < 2; ++nt) {
        const bf16_t* qp = Xb + ((size_t)(n * LSEQ + q0 + nt * 16 + ln15)) * KX + h * HS;
#pragma unroll
        for (int kk = 0; kk < 2; ++kk) {
            bf16x8 r = *(const bf16x8*)(qp + kk * 32 + quad * 8);
            bf16x8 a;
#pragma unroll
            for (int j = 0; j < 8; ++j) a[j] = (bf16_t)((float)r[j] * (0.125f * LOG2E));
            qf[nt][kk] = a;
        }
    }

    floatx4 ot[4][2];                 // O^T [dim-tile][ntile]
#pragma unroll
    for (int md = 0; md < 4; ++md)
#pragma unroll
        for (int nt = 0; nt < 2; ++nt) ot[md][nt] = (floatx4){0.f, 0.f, 0.f, 0.f};
    float lsum[2] = {0.f, 0.f};

    bf16_t* myP = &Pl[wv * 1024];     // 32 q x 32 keys, granule-swizzled
    const int qm = ln15 & 6;          // XOR mask (bit0 clear keeps b128 reads contiguous)

    for (int kt = 0; kt < LSEQ / 128; ++kt) {
        const int kb = kt * 128;
        __syncthreads();
        // ---- stage Kl: wave stages keys wv*32..+32 ----
#pragma unroll
        for (int i = 0; i < 4; ++i) {
            const int kbase = wv * 32 + i * 8;
            const int key = kbase + (lane >> 3), s = lane & 7, g = s ^ (key & 7);
            gl_lds16(Mb + ((size_t)(n * LSEQ + kb + key)) * DMODEL + h * HS + g * 8,
                     &Kl[kbase * 64]);
        }
        // ---- stage Vl: wave stages dims wv*16..+16 ----
#pragma unroll
        for (int i = 0; i < 4; ++i) {
            const int dbase = wv * 16 + i * 4;
            const int dim = dbase + (lane >> 4), s = lane & 15, g = s ^ (dim & 7);
            gl_lds16(VTg + ((size_t)((n * NH + h) * HS + dim)) * LSEQ + kb + g * 8,
                     &Vl[dbase * 128]);
        }
        __syncthreads();

#pragma unroll
        for (int half = 0; half < 2; ++half) {
            // ---- S^T (log2 domain) with C initialized to biasG ----
            floatx4 s4[4][2];
#pragma unroll
            for (int m = 0; m < 4; ++m) {
                const int key = half * 64 + m * 16 + ln15;
                floatx4 b4 = *(const floatx4*)(biasG + n * LSEQ + kb + half * 64 + m * 16 + quad * 4);
#pragma unroll
                for (int nt = 0; nt < 2; ++nt) s4[m][nt] = b4;
#pragma unroll
                for (int kk = 0; kk < 2; ++kk) {
                    const int slot = (kk * 4 + quad) ^ (ln15 & 7);
                    bf16x8 a = *(const bf16x8*)(&Kl[key * 64 + slot * 8]);
#pragma unroll
                    for (int nt = 0; nt < 2; ++nt) s4[m][nt] = mfma16(a, qf[nt][kk], s4[m][nt]);
                }
            }
            // ---- exp2 + per-lane l accumulation ----
#pragma unroll
            for (int m = 0; m < 4; ++m)
#pragma unroll
                for (int nt = 0; nt < 2; ++nt)
#pragma unroll
                    for (int reg = 0; reg < 4; ++reg) {
                        const float e = __builtin_amdgcn_exp2f(s4[m][nt][reg]);
                        s4[m][nt][reg] = e;
                        lsum[nt] += e;
                    }

            // ---- PV in 2 chunks of 32 keys through per-wave LDS ----
#pragma unroll
            for (int c = 0; c < 2; ++c) {
                // pack: m tiles {2c, 2c+1}; granule g = (m&1)*4+quad, XOR qm
#pragma unroll
                for (int mm = 0; mm < 2; ++mm) {
                    const int m = c * 2 + mm;
                    const int gsl = ((mm * 4 + quad) ^ qm) * 4;
#pragma unroll
                    for (int nt = 0; nt < 2; ++nt) {
                        const int q = nt * 16 + ln15;
                        bf16x4 p;
#pragma unroll
                        for (int reg = 0; reg < 4; ++reg) p[reg] = (bf16_t)s4[m][nt][reg];
                        *(bf16x4*)(&myP[q * 32 + gsl]) = p;
                    }
                }
                // read B-frags + MFMA
                const int cglob = half * 2 + c;
                bf16x8 pb[2];
#pragma unroll
                for (int nt = 0; nt < 2; ++nt) {
                    const int q = nt * 16 + ln15;
                    const int s16 = quad ^ (qm >> 1);
                    pb[nt] = *(const bf16x8*)(&myP[q * 32 + s16 * 8]);
                }
#pragma unroll
                for (int md = 0; md < 4; ++md) {
                    const int d = md * 16 + ln15;
                    const int vslot = (cglob * 4 + quad) ^ (d & 7);
                    bf16x8 va = *(const bf16x8*)(&Vl[d * 128 + vslot * 8]);
#pragma unroll
                    for (int nt = 0; nt < 2; ++nt) ot[md][nt] = mfma16(va, pb[nt], ot[md][nt]);
                }
            }
        }
    }

    // ---- reduce l across quads (once), write ctx^T -> Xb[:,1024:2048] ----
#pragma unroll
    for (int nt = 0; nt < 2; ++nt) {
        float t = lsum[nt];
        t += __shfl_xor(t, 16);
        t += __shfl_xor(t, 32);
        const float inv = 1.0f / t;
        const int q = q0 + nt * 16 + ln15;
        bf16_t* op = Xb + ((size_t)(n * LSEQ + q)) * KX + DMODEL + h * HS;
#pragma unroll
        for (int md = 0; md < 4; ++md) {
            bf16x4 w;
#pragma unroll
            for (int reg = 0; reg < 4; ++reg) w[reg] = (bf16_t)(ot[md][nt][reg] * inv);
            *(bf16x4*)(op + md * 16 + quad * 4) = w;
        }
    }
}

// ---------------------------------------------------------------------------
// Kernel 2: out = act( Xb @ Wb^T + bc ),  act(z)=sigmoid(z)*tanh(z).
// M=8192, N=1024, K=2048.  BM=128, BN=64, BK=64, 256 thr, 24 KB LDS,
// 4 blocks/CU.  XCD swizzle: bm = bid&63 -> XCD = bm&7, so the 16 bn-blocks
// sharing one 512 KB Xb row-slab stay on one XCD's L2.
// ---------------------------------------------------------------------------
__global__ __launch_bounds__(256, 4) void gemm_kernel(
        const bf16_t* __restrict__ Xb, const bf16_t* __restrict__ Wb,
        const float* __restrict__ bc, float* __restrict__ out) {
    __shared__ __align__(16) bf16_t Al[128 * 64];   // 16 KB
    __shared__ __align__(16) bf16_t Bl[64 * 64];    //  8 KB

    const int tid  = threadIdx.x;
    const int lane = tid & 63;
    const int wv   = tid >> 6;          // 0..3
    const int ln15 = lane & 15;
    const int quad = lane >> 4;

    const int bm = blockIdx.x & 63;     // XCD = bm&7
    const int bn = blockIdx.x >> 6;
    const int mbase = bm * 128, nbase = bn * 64;

    floatx4 acc[2][4];
#pragma unroll
    for (int i = 0; i < 2; ++i)
#pragma unroll
        for (int j = 0; j < 4; ++j) acc[i][j] = (floatx4){0.f, 0.f, 0.f, 0.f};

    for (int it = 0; it < KX / 64; ++it) {
        const int k0 = it * 64;
        __syncthreads();
        // A: 128 rows x 64 cols, 4 issues/wave (8 rows each)
#pragma unroll
        for (int i = 0; i < 4; ++i) {
            const int r0  = i * 32 + wv * 8;
            const int row = r0 + (lane >> 3);
            const int g   = (lane & 7) ^ (row & 7);
            gl_lds16(Xb + (size_t)(mbase + row) * KX + k0 + g * 8, &Al[r0 * 64]);
        }
        // B: 64 rows x 64 cols, 2 issues/wave
#pragma unroll
        for (int j = 0; j < 2; ++j) {
            const int r0  = j * 32 + wv * 8;
            const int row = r0 + (lane >> 3);
            const int g   = (lane & 7) ^ (row & 7);
            gl_lds16(Wb + (size_t)(nbase + row) * KX + k0 + g * 8, &Bl[r0 * 64]);
        }
        __syncthreads();

#pragma unroll
        for (int kk = 0; kk < 2; ++kk) {
            bf16x8 af[2], bfr[4];
#pragma unroll
            for (int mi = 0; mi < 2; ++mi) {
                const int row = wv * 32 + mi * 16 + ln15;
                const int slot = (kk * 4 + quad) ^ (row & 7);
                af[mi] = *(const bf16x8*)(&Al[row * 64 + slot * 8]);
            }
#pragma unroll
            for (int ni = 0; ni < 4; ++ni) {
                const int row = ni * 16 + ln15;
                const int slot = (kk * 4 + quad) ^ (row & 7);
                bfr[ni] = *(const bf16x8*)(&Bl[row * 64 + slot * 8]);
            }
#pragma unroll
            for (int mi = 0; mi < 2; ++mi)
#pragma unroll
                for (int ni = 0; ni < 4; ++ni)
                    acc[mi][ni] = mfma16(af[mi], bfr[ni], acc[mi][ni]);
        }
    }

    // epilogue: bias + sigmoid(z)*tanh(z)
#pragma unroll
    for (int ni = 0; ni < 4; ++ni) {
        const int col = nbase + ni * 16 + ln15;
        const float b = bc[col];
#pragma unroll
        for (int mi = 0; mi < 2; ++mi) {
#pragma unroll
            for (int reg = 0; reg < 4; ++reg) {
                const int row = mbase + wv * 32 + mi * 16 + quad * 4 + reg;
                const float z  = acc[mi][ni][reg] + b;
                const float sg = 1.0f / (1.0f + __expf(-z));
                const float th = 2.0f / (1.0f + __expf(-2.0f * z)) - 1.0f;
                out[(size_t)row * 1024 + col] = sg * th;
            }
        }
    }
}

extern "C" void kernel_launch(void* const* d_in, const int* in_sizes, int n_in,
                              void* d_out, int out_size, void* d_ws, size_t ws_size,
                              hipStream_t stream) {
    const float* inp  = (const float*)d_in[0];
    const float* mem  = (const float*)d_in[1];
    const float* mask = (const float*)d_in[2];
    const float* Wc   = (const float*)d_in[3];
    const float* bc   = (const float*)d_in[4];
    float* out = (float*)d_out;

    // ws: Xb [8192][2048] (32M) | Mb [8192][1024] (16M) | Wb [1024][2048] (4M)
    //     | VTg [8][16][64][1024] (16M) | biasG [8][1024] f32 (32K)
    bf16_t* Xb  = (bf16_t*)d_ws;
    bf16_t* Mb  = Xb + (size_t)8192 * 2048;
    bf16_t* Wb  = Mb + (size_t)8192 * 1024;
    bf16_t* VTg = Wb + (size_t)1024 * 2048;
    float* biasG = (float*)(VTg + (size_t)8192 * 1024);

    prep_kernel<<<7176, 256, 0, stream>>>(inp, mem, Wc, mask, Xb, Mb, Wb, VTg, biasG);
    attn_kernel<<<NB * NH * (LSEQ / 128), 256, 0, stream>>>(Xb, Mb, VTg, biasG);
    gemm_kernel<<<(8192 / 128) * (1024 / 64), 256, 0, stream>>>(Xb, Wb, bc, out);
}